// Round 14
// baseline (318.492 us; speedup 1.0000x reference)
//
#include <hip/hip_runtime.h>
#include <hip/hip_bf16.h>
#include <math.h>

// Problem constants (from reference)
#define BB 256
#define NN 256
#define NT (BB*NN)        // 65536 nodes per side
#define NT2 (2*NT)        // unified graph: both sides, side-1 ids offset by NT
#define NE (NT*16)        // 1048576 directed edges per side
#define DD 32
#define F1C 128
#define F2C 64
#define F3C 64
#define TT 16
#define BINS 16

// CSR bucket build (unified graph)
#define NBUCK 256
#define BSHIFT 9
#define BNODES 512
#define BCAP 10240
#define EPB 4096

typedef __attribute__((ext_vector_type(8))) short short8;   // 8 bf16 in 4 VGPRs
typedef __attribute__((ext_vector_type(4))) float f32x4;    // MFMA accumulator
typedef __attribute__((ext_vector_type(2))) float f32x2;

__device__ inline float b2f(ushort u) { return __uint_as_float(((uint)u) << 16); }
__device__ inline ushort f2b(float f) {
    uint u = __float_as_uint(f);
    return (ushort)((u + 0x7fffu + ((u >> 16) & 1u)) >> 16);
}
// fp8 e4m3 helpers (clamp to +-448 so saturation can never produce NaN)
__device__ inline float clamp8(float v) { return fminf(fmaxf(v, -448.0f), 448.0f); }
__device__ inline uchar f2f8(float v) {
    int r = __builtin_amdgcn_cvt_pk_fp8_f32(clamp8(v), 0.0f, 0, false);
    return (uchar)(r & 0xff);
}
__device__ inline void f8x8_acc(uint2 w, float* acc) {
    f32x2 p;
    p = __builtin_amdgcn_cvt_pk_f32_fp8(w.x, false); acc[0] += p.x; acc[1] += p.y;
    p = __builtin_amdgcn_cvt_pk_f32_fp8(w.x, true);  acc[2] += p.x; acc[3] += p.y;
    p = __builtin_amdgcn_cvt_pk_f32_fp8(w.y, false); acc[4] += p.x; acc[5] += p.y;
    p = __builtin_amdgcn_cvt_pk_f32_fp8(w.y, true);  acc[6] += p.x; acc[7] += p.y;
}
__device__ inline uint2 f8x8_pack(const float* v) {
    uint2 r;
    r.x = (uint)__builtin_amdgcn_cvt_pk_fp8_f32(clamp8(v[0]), clamp8(v[1]), 0, false);
    r.x = (uint)__builtin_amdgcn_cvt_pk_fp8_f32(clamp8(v[2]), clamp8(v[3]), (int)r.x, true);
    r.y = (uint)__builtin_amdgcn_cvt_pk_fp8_f32(clamp8(v[4]), clamp8(v[5]), 0, false);
    r.y = (uint)__builtin_amdgcn_cvt_pk_fp8_f32(clamp8(v[6]), clamp8(v[7]), (int)r.y, true);
    return r;
}

// ---------------- zero gcount + int histogram (must precede csr_p1 / hist_bin) ----------------
__global__ __launch_bounds__(256) void zero_k(int* __restrict__ gcount, int* __restrict__ histp) {
    int i = blockIdx.x * 256 + threadIdx.x;
    if (i < NBUCK) gcount[i] = 0;
    if (i < BB * BINS) histp[i] = 0;
}

// ---------------- CSR P1: block-local bucket sort, one gcount atomic per bucket --------------
__global__ __launch_bounds__(256) void csr_p1_k(const int* __restrict__ eq, const int* __restrict__ ec,
                                                uint* __restrict__ staged, int* __restrict__ gcount) {
    __shared__ uint s_pk[EPB];
    __shared__ int s_cnt[NBUCK];
    __shared__ int s_off[NBUCK];
    __shared__ int s_base[NBUCK];
    __shared__ int s_gb[NBUCK];
    int t = threadIdx.x;
    bool sideB = blockIdx.x >= 256;
    const int* edge = sideB ? ec : eq;
    int off = sideB ? NT : 0;
    int e0 = (blockIdx.x & 255) * EPB;
    s_cnt[t] = 0;
    __syncthreads();
    uint pk[16]; int bk[16];
#pragma unroll
    for (int j = 0; j < 16; j++) {
        int e = e0 + j * 256 + t;
        int s = edge[e] + off;
        int d = edge[NE + e] + off;
        bk[j] = d >> BSHIFT;
        pk[j] = ((uint)s << BSHIFT) | (uint)(d & (BNODES - 1));
        atomicAdd(&s_cnt[bk[j]], 1);
    }
    __syncthreads();
    s_off[t] = s_cnt[t];
    __syncthreads();
    for (int o = 1; o < NBUCK; o <<= 1) {
        int x = (t >= o) ? s_off[t - o] : 0;
        __syncthreads();
        s_off[t] += x;
        __syncthreads();
    }
    {
        int ex = s_off[t] - s_cnt[t];
        s_base[t] = ex;
        s_off[t] = ex;
        s_gb[t] = atomicAdd(&gcount[t], s_cnt[t]);
    }
    __syncthreads();
#pragma unroll
    for (int j = 0; j < 16; j++) {
        int pos = atomicAdd(&s_off[bk[j]], 1);
        s_pk[pos] = pk[j];
    }
    __syncthreads();
    int w = t >> 6, l = t & 63;
    int bsel = l >> 4, l16 = l & 15;
    for (int pb = w; pb < NBUCK / 4; pb += 4) {
        int b = pb * 4 + bsel;
        int n = s_cnt[b], st = s_base[b], gb = s_gb[b];
        if (gb + n > BCAP) n = max(0, BCAP - gb);
        for (int i = l16; i < n; i += 16)
            staged[b * BCAP + gb + i] = s_pk[st + i];
    }
}

// ---------------- CSR P2 (fused count+scan+place) ----------------
__global__ __launch_bounds__(256) void csr_p2_k(const uint* __restrict__ staged, const int* __restrict__ gcount,
                                                int* __restrict__ rp, int* __restrict__ indeg,
                                                float* __restrict__ dinv, int* __restrict__ ep) {
    int b = blockIdx.x;
    int t = threadIdx.x;
    __shared__ int cnt[BNODES];
    __shared__ int fl[BNODES];
    __shared__ int wsum[256];
    __shared__ int gsc[NBUCK];
    cnt[t] = 0; cnt[t + 256] = 0;
    gsc[t] = min(gcount[t], BCAP);
    __syncthreads();
    for (int off = 1; off < NBUCK; off <<= 1) {
        int x = (t >= off) ? gsc[t - off] : 0;
        __syncthreads();
        gsc[t] += x;
        __syncthreads();
    }
    int gbase = (b == 0) ? 0 : gsc[b - 1];
    int n = min(gcount[b], BCAP);
    const uint* sb = staged + (size_t)b * BCAP;
    int i = t;
    for (; i + 768 < n; i += 1024) {
        uint p0 = sb[i];
        uint p1 = sb[i + 256];
        uint p2 = sb[i + 512];
        uint p3 = sb[i + 768];
        atomicAdd(&cnt[p0 & (BNODES - 1)], 1);
        atomicAdd(&cnt[p1 & (BNODES - 1)], 1);
        atomicAdd(&cnt[p2 & (BNODES - 1)], 1);
        atomicAdd(&cnt[p3 & (BNODES - 1)], 1);
    }
    for (; i < n; i += 256)
        atomicAdd(&cnt[sb[i] & (BNODES - 1)], 1);
    __syncthreads();
    int base2 = t * 2;
    int c0 = cnt[base2], c1 = cnt[base2 + 1];
    int s2 = c0 + c1;
    wsum[t] = s2;
    __syncthreads();
    for (int off = 1; off < 256; off <<= 1) {
        int x = (t >= off) ? wsum[t - off] : 0;
        __syncthreads();
        wsum[t] += x;
        __syncthreads();
    }
    int p = gbase + wsum[t] - s2;
    int v0 = b * BNODES + base2;
    rp[v0] = p;          fl[base2] = p;
    indeg[v0] = c0;      dinv[v0] = rsqrtf((float)(c0 + 1));
    p += c0;
    rp[v0 + 1] = p;      fl[base2 + 1] = p;
    indeg[v0 + 1] = c1;  dinv[v0 + 1] = rsqrtf((float)(c1 + 1));
    __syncthreads();
    i = t;
    for (; i + 768 < n; i += 1024) {
        uint p0 = sb[i];
        uint p1 = sb[i + 256];
        uint p2 = sb[i + 512];
        uint p3 = sb[i + 768];
        ep[atomicAdd(&fl[p0 & (BNODES - 1)], 1)] = (int)(p0 >> BSHIFT);
        ep[atomicAdd(&fl[p1 & (BNODES - 1)], 1)] = (int)(p1 >> BSHIFT);
        ep[atomicAdd(&fl[p2 & (BNODES - 1)], 1)] = (int)(p2 >> BSHIFT);
        ep[atomicAdd(&fl[p3 & (BNODES - 1)], 1)] = (int)(p3 >> BSHIFT);
    }
    for (; i < n; i += 256) {
        uint pk = sb[i];
        ep[atomicAdd(&fl[pk & (BNODES - 1)], 1)] = (int)(pk >> BSHIFT);
    }
}

// ---------------- f32 -> pre-scaled bf16 (x̃ = dinv*x) + weight conversions (block-split) ----
__global__ __launch_bounds__(256) void cvt2w_k(const float* __restrict__ a, const float* __restrict__ b,
                                               const float* __restrict__ dinv, ushort* __restrict__ out,
                                               const float* __restrict__ W1, const float* __restrict__ W2,
                                               const float* __restrict__ W3, ushort* __restrict__ Wt1,
                                               ushort* __restrict__ Wt2, uchar* __restrict__ Wt3f8) {
    const int NB_X = NT2 * DD / 4 / 256;               // 2048 feature blocks
    if (blockIdx.x < NB_X) {
        int i = blockIdx.x * 256 + threadIdx.x;
        const int per = NT * DD / 4;
        bool sideB = i >= per;
        const float4* src = (const float4*)(sideB ? b : a);
        float4 v = src[sideB ? i - per : i];
        float dv = dinv[i / (DD / 4)];
        ushort4 o;
        o.x = f2b(v.x * dv); o.y = f2b(v.y * dv); o.z = f2b(v.z * dv); o.w = f2b(v.w * dv);
        ((ushort4*)out)[i] = o;
    } else {
        int i = (blockIdx.x - NB_X) * 256 + threadIdx.x;   // 0..16383
        if (i < DD * F1C)  { int k = i / F1C, n = i % F1C; Wt1[n * DD + k]  = f2b(W1[i]); }
        if (i < F1C * F2C) { int k = i / F2C, n = i % F2C; Wt2[n * F1C + k] = f2b(W2[i]); }
        if (i < F2C * F3C) { int k = i / F3C, n = i % F3C; Wt3f8[n * F2C + k] = f2f8(W3[i]); }
    }
}

// ---------------- GCN aggregation, bf16 rows (layer 1, F=32) ----------------
template<int F, bool BIAS, bool RELU>
__global__ __launch_bounds__(256) void agg_bf_k(const ushort* __restrict__ in, const int* __restrict__ rp,
                                                const int* __restrict__ indeg, const int* __restrict__ ep,
                                                const float* __restrict__ dinv,
                                                const float* __restrict__ bias, ushort* __restrict__ out) {
    constexpr int LPV = F / 8;
    constexpr int VPB = 256 / LPV;
    int g = threadIdx.x / LPV;
    int l = threadIdx.x % LPV;
    int v = blockIdx.x * VPB + g;
    float dv = dinv[v];
    short8 rs = *(const short8*)(in + (size_t)v * F + l * 8);
    float acc[8];
#pragma unroll
    for (int j = 0; j < 8; j++) acc[j] = b2f((ushort)rs[j]);
    int start = rp[v];
    int cnt   = indeg[v];
    int i = 0;
    for (; i + 4 <= cnt; i += 4) {
        int s0 = ep[start + i];
        int s1 = ep[start + i + 1];
        int s2 = ep[start + i + 2];
        int s3 = ep[start + i + 3];
        short8 r0 = *(const short8*)(in + (size_t)s0 * F + l * 8);
        short8 r1 = *(const short8*)(in + (size_t)s1 * F + l * 8);
        short8 r2 = *(const short8*)(in + (size_t)s2 * F + l * 8);
        short8 r3 = *(const short8*)(in + (size_t)s3 * F + l * 8);
#pragma unroll
        for (int j = 0; j < 8; j++) {
            acc[j] += b2f((ushort)r0[j]);
            acc[j] += b2f((ushort)r1[j]);
            acc[j] += b2f((ushort)r2[j]);
            acc[j] += b2f((ushort)r3[j]);
        }
    }
    for (; i < cnt; i++) {
        int s0 = ep[start + i];
        short8 r0 = *(const short8*)(in + (size_t)s0 * F + l * 8);
#pragma unroll
        for (int j = 0; j < 8; j++) acc[j] += b2f((ushort)r0[j]);
    }
    short8 o;
#pragma unroll
    for (int j = 0; j < 8; j++) {
        float x = dv * acc[j];
        if (BIAS) x += bias[l * 8 + j];
        if (RELU) x = fmaxf(x, 0.0f);
        o[j] = (short)f2b(x);
    }
    *(short8*)(out + (size_t)v * F + l * 8) = o;
}

// ---------------- GCN aggregation, fp8 rows (F=64: one 64B line per gather) ----------------
template<bool OUT_BF16, bool BIAS, bool RELU>
__global__ __launch_bounds__(256) void agg_f8_k(const uchar* __restrict__ in, const int* __restrict__ rp,
                                                const int* __restrict__ indeg, const int* __restrict__ ep,
                                                const float* __restrict__ dinv,
                                                const float* __restrict__ bias, void* __restrict__ outp) {
    int g = threadIdx.x >> 3;          // 32 vertices per block
    int l = threadIdx.x & 7;           // 8 lanes x 8 fp8 = 64 B row
    int v = blockIdx.x * 32 + g;
    float dv = dinv[v];
    float acc[8] = {0, 0, 0, 0, 0, 0, 0, 0};
    f8x8_acc(*(const uint2*)(in + (size_t)v * 64 + l * 8), acc);   // self term
    int start = rp[v];
    int cnt   = indeg[v];
    int i = 0;
    for (; i + 4 <= cnt; i += 4) {
        int s0 = ep[start + i];
        int s1 = ep[start + i + 1];
        int s2 = ep[start + i + 2];
        int s3 = ep[start + i + 3];
        uint2 g0 = *(const uint2*)(in + (size_t)s0 * 64 + l * 8);
        uint2 g1 = *(const uint2*)(in + (size_t)s1 * 64 + l * 8);
        uint2 g2 = *(const uint2*)(in + (size_t)s2 * 64 + l * 8);
        uint2 g3 = *(const uint2*)(in + (size_t)s3 * 64 + l * 8);
        f8x8_acc(g0, acc); f8x8_acc(g1, acc); f8x8_acc(g2, acc); f8x8_acc(g3, acc);
    }
    for (; i < cnt; i++) {
        int s0 = ep[start + i];
        f8x8_acc(*(const uint2*)(in + (size_t)s0 * 64 + l * 8), acc);
    }
#pragma unroll
    for (int j = 0; j < 8; j++) {
        float x = dv * acc[j];
        if (BIAS) x += bias[l * 8 + j];
        if (RELU) x = fmaxf(x, 0.0f);
        acc[j] = x;
    }
    if (OUT_BF16) {
        short8 o;
#pragma unroll
        for (int j = 0; j < 8; j++) o[j] = (short)f2b(acc[j]);
        *(short8*)((ushort*)outp + (size_t)v * 64 + l * 8) = o;
    } else {
        *(uint2*)((uchar*)outp + (size_t)v * 64 + l * 8) = f8x8_pack(acc);
    }
}

// ---------------- fused GEMM1+GEMM2: h1=relu(xa@W1+b1) [LDS] ; out8=(h1@W2)*dinv ----------
__global__ __launch_bounds__(256) void gemm12_k(const ushort* __restrict__ xa,
                                                const ushort* __restrict__ Wt1,
                                                const float* __restrict__ b1,
                                                const ushort* __restrict__ Wt2,
                                                const float* __restrict__ dinv,
                                                uchar* __restrict__ h8a) {
    __shared__ ushort s_h1[128][136];
    int w = threadIdx.x >> 6, lane = threadIdx.x & 63;
    int r16 = lane & 15, quad = lane >> 4, koff = quad * 8;
    size_t rows0 = (size_t)blockIdx.x * 128;

    short8 af1[2];
#pragma unroll
    for (int mt = 0; mt < 2; mt++)
        af1[mt] = *(const short8*)(xa + (rows0 + (w * 2 + mt) * 16 + r16) * 32 + koff);
#pragma unroll
    for (int nt = 0; nt < 8; nt++) {
        short8 bfr = *(const short8*)(Wt1 + (size_t)(nt * 16 + r16) * 32 + koff);
        f32x4 acc[2] = {{0.f,0.f,0.f,0.f},{0.f,0.f,0.f,0.f}};
        acc[0] = __builtin_amdgcn_mfma_f32_16x16x32_bf16(af1[0], bfr, acc[0], 0, 0, 0);
        acc[1] = __builtin_amdgcn_mfma_f32_16x16x32_bf16(af1[1], bfr, acc[1], 0, 0, 0);
        int col = nt * 16 + r16;
        float bc = b1[col];
#pragma unroll
        for (int mt = 0; mt < 2; mt++)
#pragma unroll
            for (int r = 0; r < 4; r++) {
                int rl = (w * 2 + mt) * 16 + quad * 4 + r;
                s_h1[rl][col] = f2b(fmaxf(acc[mt][r] + bc, 0.0f));
            }
    }
    __syncthreads();

    short8 af2[4][2];
#pragma unroll
    for (int kc = 0; kc < 4; kc++)
#pragma unroll
        for (int mt = 0; mt < 2; mt++)
            af2[kc][mt] = *(const short8*)&s_h1[(w * 2 + mt) * 16 + r16][kc * 32 + koff];
    float dvr[2][4];
#pragma unroll
    for (int mt = 0; mt < 2; mt++)
#pragma unroll
        for (int r = 0; r < 4; r++)
            dvr[mt][r] = dinv[rows0 + (w * 2 + mt) * 16 + quad * 4 + r];
#pragma unroll
    for (int nt = 0; nt < 4; nt++) {
        f32x4 acc[2] = {{0.f,0.f,0.f,0.f},{0.f,0.f,0.f,0.f}};
#pragma unroll
        for (int kc = 0; kc < 4; kc++) {
            short8 bfr = *(const short8*)(Wt2 + (size_t)(nt * 16 + r16) * 128 + kc * 32 + koff);
            acc[0] = __builtin_amdgcn_mfma_f32_16x16x32_bf16(af2[kc][0], bfr, acc[0], 0, 0, 0);
            acc[1] = __builtin_amdgcn_mfma_f32_16x16x32_bf16(af2[kc][1], bfr, acc[1], 0, 0, 0);
        }
#pragma unroll
        for (int mt = 0; mt < 2; mt++)
#pragma unroll
            for (int r = 0; r < 4; r++) {
                size_t row = rows0 + (w * 2 + mt) * 16 + quad * 4 + r;
                int col = nt * 16 + r16;
                h8a[row * 64 + col] = f2f8(acc[mt][r] * dvr[mt][r]);
            }
    }
}

// ---------------- fp8 GEMM via MFMA (K=64, N=64) ----------------
__global__ __launch_bounds__(256) void gemm_f8_k(const uchar* __restrict__ A8,
                                                 const uchar* __restrict__ Wt8,
                                                 const float* __restrict__ dinv,
                                                 uchar* __restrict__ out8) {
    int w = threadIdx.x >> 6, lane = threadIdx.x & 63;
    int r16 = lane & 15, koff = (lane >> 4) * 8;
    size_t rows0 = (size_t)blockIdx.x * 128;

    long af[2][2];
#pragma unroll
    for (int kc = 0; kc < 2; kc++)
#pragma unroll
        for (int mt = 0; mt < 2; mt++)
            af[kc][mt] = *(const long*)(A8 + (rows0 + (w * 2 + mt) * 16 + r16) * 64 + kc * 32 + koff);

    float dvr[2][4];
#pragma unroll
    for (int mt = 0; mt < 2; mt++)
#pragma unroll
        for (int r = 0; r < 4; r++)
            dvr[mt][r] = dinv[rows0 + (w * 2 + mt) * 16 + (lane >> 4) * 4 + r];

#pragma unroll
    for (int nt = 0; nt < 4; nt++) {
        f32x4 acc[2] = {{0.f,0.f,0.f,0.f},{0.f,0.f,0.f,0.f}};
#pragma unroll
        for (int kc = 0; kc < 2; kc++) {
            long b = *(const long*)(Wt8 + (size_t)(nt * 16 + r16) * 64 + kc * 32 + koff);
            acc[0] = __builtin_amdgcn_mfma_f32_16x16x32_fp8_fp8(af[kc][0], b, acc[0], 0, 0, 0);
            acc[1] = __builtin_amdgcn_mfma_f32_16x16x32_fp8_fp8(af[kc][1], b, acc[1], 0, 0, 0);
        }
#pragma unroll
        for (int mt = 0; mt < 2; mt++) {
#pragma unroll
            for (int r = 0; r < 4; r++) {
                size_t row = rows0 + (w * 2 + mt) * 16 + (lane >> 4) * 4 + r;
                int col = nt * 16 + (lane & 15);
                out8[row * 64 + col] = f2f8(acc[mt][r] * dvr[mt][r]);
            }
        }
    }
}

// ---------------- attention pooling: LDS-resident (unified fin) ----------------
__global__ __launch_bounds__(256) void pool_k(const ushort* __restrict__ fin,
                                              const int* __restrict__ qsz, const int* __restrict__ csz,
                                              const float* __restrict__ attn_w, float* __restrict__ e_out) {
    int b = blockIdx.x & 255;
    bool is_c = blockIdx.x >= BB;
    const ushort* emb = fin + (size_t)blockIdx.x * NN * F3C;
    float size = (float)((is_c ? csz : qsz)[b]);
    float* eo = e_out + (is_c ? BB * F3C : 0) + b * F3C;

    int t = threadIdx.x;
    int f = t & 63;
    int w = t >> 6;

    __shared__ float s_emb[NN][F3C + 1];
    __shared__ float s_red[4][64];
    __shared__ float s_sq[64];
    __shared__ float s_ctx[64];
    __shared__ float s_sig[NN];

    float psum = 0.0f;
    for (int n = w; n < NN; n += 4) {
        float v = b2f(emb[n * F3C + f]);
        s_emb[n][f] = v;
        psum += v;
    }
    s_red[w][f] = psum;
    __syncthreads();

    if (w == 0) {
        s_sq[f] = s_red[0][f] + s_red[1][f] + s_red[2][f] + s_red[3][f];
        float acc = 0.0f;
        for (int k = 0; k < 64; k++) acc += s_sq[k] * attn_w[k * 64 + f];
        s_ctx[f] = tanhf(acc / size);
    }
    __syncthreads();

    {
        float acc = 0.0f;
#pragma unroll 8
        for (int k = 0; k < 64; k++) acc += s_emb[t][k] * s_ctx[k];
        s_sig[t] = 1.0f / (1.0f + expf(-acc));
    }
    __syncthreads();

    float eacc = 0.0f;
#pragma unroll 8
    for (int i = 0; i < 64; i++) {
        int n = w * 64 + i;
        eacc += s_sig[n] * s_emb[n][f];
    }
    s_red[w][f] = eacc;
    __syncthreads();
    if (w == 0) eo[f] = s_red[0][f] + s_red[1][f] + s_red[2][f] + s_red[3][f];
}

// ---------------- histogram pass A: min/max partials, 4 blocks per pair ----------------
// block q-range: 64 rows (wave w covers rows quarter*64 + w*16 .. +16)
__global__ __launch_bounds__(256) void hist_mm_k(const ushort* __restrict__ fin,
                                                 float* __restrict__ pmn, float* __restrict__ pmx) {
    int b = blockIdx.x >> 2, quarter = blockIdx.x & 3;
    const ushort* qb = fin + (size_t)b * NN * 64;
    const ushort* cb = fin + (size_t)(NT + b * NN) * 64;
    int lane = threadIdx.x & 63;
    int w = threadIdx.x >> 6;
    int r16 = lane & 15, koff = (lane >> 4) * 8;
    int qrow = quarter * 64 + w * 16 + r16;
    short8 a0 = *(const short8*)(qb + qrow * 64 + koff);
    short8 a1 = *(const short8*)(qb + qrow * 64 + 32 + koff);

    float mn = 1e30f, mx = -1e30f;
    for (int mt = 0; mt < 16; mt++) {
        int crow = mt * 16 + r16;
        short8 b0 = *(const short8*)(cb + crow * 64 + koff);
        short8 b1 = *(const short8*)(cb + crow * 64 + 32 + koff);
        f32x4 acc = {0.0f, 0.0f, 0.0f, 0.0f};
        acc = __builtin_amdgcn_mfma_f32_16x16x32_bf16(a0, b0, acc, 0, 0, 0);
        acc = __builtin_amdgcn_mfma_f32_16x16x32_bf16(a1, b1, acc, 0, 0, 0);
        mn = fminf(mn, fminf(fminf(acc[0], acc[1]), fminf(acc[2], acc[3])));
        mx = fmaxf(mx, fmaxf(fmaxf(acc[0], acc[1]), fmaxf(acc[2], acc[3])));
    }
    for (int off = 32; off; off >>= 1) {
        mn = fminf(mn, __shfl_xor(mn, off, 64));
        mx = fmaxf(mx, __shfl_xor(mx, off, 64));
    }
    __shared__ float smn[4], smx[4];
    if (lane == 0) { smn[w] = mn; smx[w] = mx; }
    __syncthreads();
    if (threadIdx.x == 0) {
        pmn[blockIdx.x] = fminf(fminf(smn[0], smn[1]), fminf(smn[2], smn[3]));
        pmx[blockIdx.x] = fmaxf(fmaxf(smx[0], smx[1]), fmaxf(smx[2], smx[3]));
    }
}

// ---------------- histogram pass B: bin + atomic merge, 4 blocks per pair ----------------
__global__ __launch_bounds__(256) void hist_bin_k(const ushort* __restrict__ fin,
                                                  const float* __restrict__ pmn, const float* __restrict__ pmx,
                                                  int* __restrict__ histp) {
    int b = blockIdx.x >> 2, quarter = blockIdx.x & 3;
    const ushort* qb = fin + (size_t)b * NN * 64;
    const ushort* cb = fin + (size_t)(NT + b * NN) * 64;
    int lane = threadIdx.x & 63;
    int w = threadIdx.x >> 6;
    int r16 = lane & 15, koff = (lane >> 4) * 8;
    int qrow = quarter * 64 + w * 16 + r16;
    short8 a0 = *(const short8*)(qb + qrow * 64 + koff);
    short8 a1 = *(const short8*)(qb + qrow * 64 + 32 + koff);

    float mn = fminf(fminf(pmn[4 * b], pmn[4 * b + 1]), fminf(pmn[4 * b + 2], pmn[4 * b + 3]));
    float mx = fmaxf(fmaxf(pmx[4 * b], pmx[4 * b + 1]), fmaxf(pmx[4 * b + 2], pmx[4 * b + 3]));
    float scale = 16.0f / fmaxf(mx - mn, 1e-12f);

    __shared__ int h[16 * 256];
#pragma unroll
    for (int i = 0; i < 16; i++) h[i * 256 + threadIdx.x] = 0;
    __syncthreads();

    for (int mt = 0; mt < 16; mt++) {
        int crow = mt * 16 + r16;
        short8 b0 = *(const short8*)(cb + crow * 64 + koff);
        short8 b1 = *(const short8*)(cb + crow * 64 + 32 + koff);
        f32x4 acc = {0.0f, 0.0f, 0.0f, 0.0f};
        acc = __builtin_amdgcn_mfma_f32_16x16x32_bf16(a0, b0, acc, 0, 0, 0);
        acc = __builtin_amdgcn_mfma_f32_16x16x32_bf16(a1, b1, acc, 0, 0, 0);
#pragma unroll
        for (int r = 0; r < 4; r++) {
            int bin = (int)floorf((acc[r] - mn) * scale);
            bin = min(max(bin, 0), 15);
            h[bin * 256 + threadIdx.x] += 1;
        }
    }
    __syncthreads();
    __shared__ int hp[16][16];
    int bb = threadIdx.x >> 4, part = threadIdx.x & 15;
    int sum = 0;
#pragma unroll
    for (int j = 0; j < 16; j++) sum += h[bb * 256 + part * 16 + j];
    hp[bb][part] = sum;
    __syncthreads();
    if (threadIdx.x < 16) {
        int s = 0;
#pragma unroll
        for (int j = 0; j < 16; j++) s += hp[threadIdx.x][j];
        atomicAdd(&histp[b * 16 + threadIdx.x], s);
    }
}

// ---------------- NTN + head fused ----------------
__global__ __launch_bounds__(256) void ntn_final_k(const float* __restrict__ e, const float* __restrict__ A,
                                                   const float* __restrict__ bw, const float* __restrict__ bias,
                                                   const int* __restrict__ histp,
                                                   const float* __restrict__ fc1w, const float* __restrict__ fc1b,
                                                   const float* __restrict__ fc2w, const float* __restrict__ fc2b,
                                                   const int* __restrict__ qsz, const int* __restrict__ csz,
                                                   float* __restrict__ out) {
    int b = blockIdx.x;
    int t = threadIdx.x;
    __shared__ float s_e1[64], s_e2[64];
    __shared__ float s_ntn[16];
    __shared__ float s_s[32];
    __shared__ float s_a[16];
    if (t < 64) s_e1[t] = e[b * 64 + t];
    else if (t < 128) s_e2[t - 64] = e[BB * 64 + b * 64 + (t - 64)];
    if (t < 16) s_ntn[t] = 0.0f;
    __syncthreads();
#pragma unroll
    for (int r = 0; r < 4; r++) {
        int idx = t + r * 256;
        int tt = idx >> 6, i = idx & 63;
        const float* Ar = A + (size_t)idx * 64;
        float acc = 0.0f;
        for (int j = 0; j < 64; j++) acc += Ar[j] * s_e2[j];
        atomicAdd(&s_ntn[tt], s_e1[i] * acc);
    }
    __syncthreads();
    if (t < 16) {
        float acc = s_ntn[t] + bias[t];
        for (int k = 0; k < 64; k++) acc += s_e1[k] * bw[k * 16 + t];
        for (int k = 0; k < 64; k++) acc += s_e2[k] * bw[(64 + k) * 16 + t];
        s_s[t] = fmaxf(acc, 0.0f);
        s_s[16 + t] = (float)histp[b * 16 + t] * (1.0f / 65536.0f);
    }
    __syncthreads();
    if (t < 16) {
        float a = fc1b[t];
        for (int k = 0; k < 32; k++) a += s_s[k] * fc1w[k * 16 + t];
        s_a[t] = fmaxf(a, 0.0f);
    }
    __syncthreads();
    if (t == 0) {
        float z = fc2b[0];
        for (int j = 0; j < 16; j++) z += s_a[j] * fc2w[j];
        float nz = -z;
        float sp = (nz > 20.0f) ? nz : log1pf(expf(nz));   // stable -log(sigmoid(z))
        out[b] = 0.5f * (float)(qsz[b] + csz[b]) * sp;
    }
}

// ---------------- launch ----------------
extern "C" void kernel_launch(void* const* d_in, const int* in_sizes, int n_in,
                              void* d_out, int out_size, void* d_ws, size_t ws_size,
                              hipStream_t stream) {
    const float* x_q    = (const float*)d_in[0];
    const int*   edge_q = (const int*)d_in[1];
    const float* x_c    = (const float*)d_in[2];
    const int*   edge_c = (const int*)d_in[3];
    const int*   qsz    = (const int*)d_in[4];
    const int*   csz    = (const int*)d_in[5];
    const float* W1 = (const float*)d_in[6];
    const float* b1 = (const float*)d_in[7];
    const float* W2 = (const float*)d_in[8];
    const float* b2 = (const float*)d_in[9];
    const float* W3 = (const float*)d_in[10];
    const float* b3 = (const float*)d_in[11];
    const float* attn_w  = (const float*)d_in[12];
    const float* ntn_a   = (const float*)d_in[13];
    const float* ntn_b   = (const float*)d_in[14];
    const float* ntn_bias= (const float*)d_in[15];
    const float* fc1w = (const float*)d_in[16];
    const float* fc1b = (const float*)d_in[17];
    const float* fc2w = (const float*)d_in[18];
    const float* fc2b = (const float*)d_in[19];
    float* out = (float*)d_out;

    char* w = (char*)d_ws;
    auto alloc = [&](size_t bytes) -> void* {
        void* p = (void*)w;
        w += (bytes + 255) & ~(size_t)255;
        return p;
    };
    int*    rp     = (int*)alloc((size_t)NT2 * 4);
    int*    indeg  = (int*)alloc((size_t)NT2 * 4);
    float*  dinv   = (float*)alloc((size_t)NT2 * 4);
    int*    gcount = (int*)alloc(NBUCK * 4);
    uint*   staged = (uint*)alloc((size_t)NBUCK * BCAP * 4);   // 10.5 MB packed
    int*    ep     = (int*)alloc((size_t)2 * NE * 4);           // 8.4 MB (src only)
    ushort* xb     = (ushort*)alloc((size_t)NT2 * 32 * 2);
    ushort* xa     = (ushort*)alloc((size_t)NT2 * 32 * 2);
    uchar*  h8a    = (uchar*)alloc((size_t)NT2 * 64);           // fp8 64-d scratch
    uchar*  h8b    = (uchar*)alloc((size_t)NT2 * 64);           // fp8 64-d scratch
    ushort* fin    = (ushort*)alloc((size_t)NT2 * 64 * 2);      // qfin | cfin (bf16)
    ushort* Wt1    = (ushort*)alloc((size_t)DD * F1C * 2);
    ushort* Wt2    = (ushort*)alloc((size_t)F1C * F2C * 2);
    uchar*  Wt3f8  = (uchar*)alloc((size_t)F2C * F3C);
    float*  e12    = (float*)alloc(2 * BB * 64 * 4);
    float*  pmn    = (float*)alloc(1024 * 4);
    float*  pmx    = (float*)alloc(1024 * 4);
    int*    histp  = (int*)alloc(BB * BINS * 4);

    // CSR build (unified graph); zero_k also zeroes the int histogram
    zero_k<<<16, 256, 0, stream>>>(gcount, histp);
    csr_p1_k<<<512, 256, 0, stream>>>(edge_q, edge_c, staged, gcount);
    csr_p2_k<<<NBUCK, 256, 0, stream>>>(staged, gcount, rp, indeg, dinv, ep);

    // features -> pre-scaled bf16 + weight conversions (one launch)
    cvt2w_k<<<NT2 * 32 / 4 / 256 + 64, 256, 0, stream>>>(x_q, x_c, dinv, xb,
                                                         W1, W2, W3, Wt1, Wt2, Wt3f8);

    // GNN: agg1 -> fused gemm1+2 -> agg2 -> gemm3(fp8) -> agg3
    agg_bf_k<32, false, false><<<NT2 / 64, 256, 0, stream>>>(xb, rp, indeg, ep, dinv, nullptr, xa);
    gemm12_k<<<NT2 / 128, 256, 0, stream>>>(xa, Wt1, b1, Wt2, dinv, h8a);
    agg_f8_k<false, true, true><<<NT2 / 32, 256, 0, stream>>>(h8a, rp, indeg, ep, dinv, b2, h8b);
    gemm_f8_k<<<NT2 / 128, 256, 0, stream>>>(h8b, Wt3f8, dinv, h8a);
    agg_f8_k<true, true, false><<<NT2 / 32, 256, 0, stream>>>(h8a, rp, indeg, ep, dinv, b3, fin);

    // pool (512 blocks) + histogram (4 blocks/pair, 1024 blocks x 2 passes) + NTN+head
    pool_k<<<512, 256, 0, stream>>>(fin, qsz, csz, attn_w, e12);
    hist_mm_k<<<1024, 256, 0, stream>>>(fin, pmn, pmx);
    hist_bin_k<<<1024, 256, 0, stream>>>(fin, pmn, pmx, histp);
    ntn_final_k<<<BB, 256, 0, stream>>>(e12, ntn_a, ntn_b, ntn_bias, histp,
                                        fc1w, fc1b, fc2w, fc2b, qsz, csz, out);
}

// Round 15
// 285.623 us; speedup vs baseline: 1.1151x; 1.1151x over previous
//
#include <hip/hip_runtime.h>
#include <hip/hip_bf16.h>
#include <math.h>

// Problem constants (from reference)
#define BB 256
#define NN 256
#define NT (BB*NN)        // 65536 nodes per side
#define NT2 (2*NT)        // unified graph: both sides, side-1 ids offset by NT
#define NE (NT*16)        // 1048576 directed edges per side
#define DD 32
#define F1C 128
#define F2C 64
#define F3C 64
#define TT 16
#define BINS 16

// CSR bucket build (unified graph)
#define NBUCK 256
#define BSHIFT 9
#define BNODES 512
#define BCAP 10240
#define EPB 4096

typedef __attribute__((ext_vector_type(8))) short short8;   // 8 bf16 in 4 VGPRs
typedef __attribute__((ext_vector_type(4))) float f32x4;    // MFMA accumulator
typedef __attribute__((ext_vector_type(2))) float f32x2;

__device__ inline float b2f(ushort u) { return __uint_as_float(((uint)u) << 16); }
__device__ inline ushort f2b(float f) {
    uint u = __float_as_uint(f);
    return (ushort)((u + 0x7fffu + ((u >> 16) & 1u)) >> 16);
}
// fp8 e4m3 helpers (clamp to +-448 so saturation can never produce NaN)
__device__ inline float clamp8(float v) { return fminf(fmaxf(v, -448.0f), 448.0f); }
__device__ inline uchar f2f8(float v) {
    int r = __builtin_amdgcn_cvt_pk_fp8_f32(clamp8(v), 0.0f, 0, false);
    return (uchar)(r & 0xff);
}
__device__ inline void f8x8_acc(uint2 w, float* acc) {
    f32x2 p;
    p = __builtin_amdgcn_cvt_pk_f32_fp8(w.x, false); acc[0] += p.x; acc[1] += p.y;
    p = __builtin_amdgcn_cvt_pk_f32_fp8(w.x, true);  acc[2] += p.x; acc[3] += p.y;
    p = __builtin_amdgcn_cvt_pk_f32_fp8(w.y, false); acc[4] += p.x; acc[5] += p.y;
    p = __builtin_amdgcn_cvt_pk_f32_fp8(w.y, true);  acc[6] += p.x; acc[7] += p.y;
}
__device__ inline uint2 f8x8_pack(const float* v) {
    uint2 r;
    r.x = (uint)__builtin_amdgcn_cvt_pk_fp8_f32(clamp8(v[0]), clamp8(v[1]), 0, false);
    r.x = (uint)__builtin_amdgcn_cvt_pk_fp8_f32(clamp8(v[2]), clamp8(v[3]), (int)r.x, true);
    r.y = (uint)__builtin_amdgcn_cvt_pk_fp8_f32(clamp8(v[4]), clamp8(v[5]), 0, false);
    r.y = (uint)__builtin_amdgcn_cvt_pk_fp8_f32(clamp8(v[6]), clamp8(v[7]), (int)r.y, true);
    return r;
}

// ---------------- zero gcount (must precede csr_p1) ----------------
__global__ __launch_bounds__(256) void zero_k(int* __restrict__ gcount) {
    gcount[threadIdx.x] = 0;
}

// ---------------- CSR P1: block-local bucket sort, one gcount atomic per bucket --------------
__global__ __launch_bounds__(256) void csr_p1_k(const int* __restrict__ eq, const int* __restrict__ ec,
                                                uint* __restrict__ staged, int* __restrict__ gcount) {
    __shared__ uint s_pk[EPB];
    __shared__ int s_cnt[NBUCK];
    __shared__ int s_off[NBUCK];
    __shared__ int s_base[NBUCK];
    __shared__ int s_gb[NBUCK];
    int t = threadIdx.x;
    bool sideB = blockIdx.x >= 256;
    const int* edge = sideB ? ec : eq;
    int off = sideB ? NT : 0;
    int e0 = (blockIdx.x & 255) * EPB;
    s_cnt[t] = 0;
    __syncthreads();
    uint pk[16]; int bk[16];
#pragma unroll
    for (int j = 0; j < 16; j++) {
        int e = e0 + j * 256 + t;
        int s = edge[e] + off;
        int d = edge[NE + e] + off;
        bk[j] = d >> BSHIFT;
        pk[j] = ((uint)s << BSHIFT) | (uint)(d & (BNODES - 1));
        atomicAdd(&s_cnt[bk[j]], 1);
    }
    __syncthreads();
    s_off[t] = s_cnt[t];
    __syncthreads();
    for (int o = 1; o < NBUCK; o <<= 1) {
        int x = (t >= o) ? s_off[t - o] : 0;
        __syncthreads();
        s_off[t] += x;
        __syncthreads();
    }
    {
        int ex = s_off[t] - s_cnt[t];
        s_base[t] = ex;
        s_off[t] = ex;
        s_gb[t] = atomicAdd(&gcount[t], s_cnt[t]);
    }
    __syncthreads();
#pragma unroll
    for (int j = 0; j < 16; j++) {
        int pos = atomicAdd(&s_off[bk[j]], 1);
        s_pk[pos] = pk[j];
    }
    __syncthreads();
    int w = t >> 6, l = t & 63;
    int bsel = l >> 4, l16 = l & 15;
    for (int pb = w; pb < NBUCK / 4; pb += 4) {
        int b = pb * 4 + bsel;
        int n = s_cnt[b], st = s_base[b], gb = s_gb[b];
        if (gb + n > BCAP) n = max(0, BCAP - gb);
        for (int i = l16; i < n; i += 16)
            staged[b * BCAP + gb + i] = s_pk[st + i];
    }
}

// ---------------- CSR P2 (fused count+scan+place) ----------------
__global__ __launch_bounds__(256) void csr_p2_k(const uint* __restrict__ staged, const int* __restrict__ gcount,
                                                int* __restrict__ rp, int* __restrict__ indeg,
                                                float* __restrict__ dinv, int* __restrict__ ep) {
    int b = blockIdx.x;
    int t = threadIdx.x;
    __shared__ int cnt[BNODES];
    __shared__ int fl[BNODES];
    __shared__ int wsum[256];
    __shared__ int gsc[NBUCK];
    cnt[t] = 0; cnt[t + 256] = 0;
    gsc[t] = min(gcount[t], BCAP);
    __syncthreads();
    for (int off = 1; off < NBUCK; off <<= 1) {
        int x = (t >= off) ? gsc[t - off] : 0;
        __syncthreads();
        gsc[t] += x;
        __syncthreads();
    }
    int gbase = (b == 0) ? 0 : gsc[b - 1];
    int n = min(gcount[b], BCAP);
    const uint* sb = staged + (size_t)b * BCAP;
    int i = t;
    for (; i + 768 < n; i += 1024) {
        uint p0 = sb[i];
        uint p1 = sb[i + 256];
        uint p2 = sb[i + 512];
        uint p3 = sb[i + 768];
        atomicAdd(&cnt[p0 & (BNODES - 1)], 1);
        atomicAdd(&cnt[p1 & (BNODES - 1)], 1);
        atomicAdd(&cnt[p2 & (BNODES - 1)], 1);
        atomicAdd(&cnt[p3 & (BNODES - 1)], 1);
    }
    for (; i < n; i += 256)
        atomicAdd(&cnt[sb[i] & (BNODES - 1)], 1);
    __syncthreads();
    int base2 = t * 2;
    int c0 = cnt[base2], c1 = cnt[base2 + 1];
    int s2 = c0 + c1;
    wsum[t] = s2;
    __syncthreads();
    for (int off = 1; off < 256; off <<= 1) {
        int x = (t >= off) ? wsum[t - off] : 0;
        __syncthreads();
        wsum[t] += x;
        __syncthreads();
    }
    int p = gbase + wsum[t] - s2;
    int v0 = b * BNODES + base2;
    rp[v0] = p;          fl[base2] = p;
    indeg[v0] = c0;      dinv[v0] = rsqrtf((float)(c0 + 1));
    p += c0;
    rp[v0 + 1] = p;      fl[base2 + 1] = p;
    indeg[v0 + 1] = c1;  dinv[v0 + 1] = rsqrtf((float)(c1 + 1));
    __syncthreads();
    i = t;
    for (; i + 768 < n; i += 1024) {
        uint p0 = sb[i];
        uint p1 = sb[i + 256];
        uint p2 = sb[i + 512];
        uint p3 = sb[i + 768];
        ep[atomicAdd(&fl[p0 & (BNODES - 1)], 1)] = (int)(p0 >> BSHIFT);
        ep[atomicAdd(&fl[p1 & (BNODES - 1)], 1)] = (int)(p1 >> BSHIFT);
        ep[atomicAdd(&fl[p2 & (BNODES - 1)], 1)] = (int)(p2 >> BSHIFT);
        ep[atomicAdd(&fl[p3 & (BNODES - 1)], 1)] = (int)(p3 >> BSHIFT);
    }
    for (; i < n; i += 256) {
        uint pk = sb[i];
        ep[atomicAdd(&fl[pk & (BNODES - 1)], 1)] = (int)(pk >> BSHIFT);
    }
}

// ---------------- f32 -> pre-scaled bf16 (x̃ = dinv*x) + weight conversions (block-split) ----
__global__ __launch_bounds__(256) void cvt2w_k(const float* __restrict__ a, const float* __restrict__ b,
                                               const float* __restrict__ dinv, ushort* __restrict__ out,
                                               const float* __restrict__ W1, const float* __restrict__ W2,
                                               const float* __restrict__ W3, ushort* __restrict__ Wt1,
                                               ushort* __restrict__ Wt2, uchar* __restrict__ Wt3f8) {
    const int NB_X = NT2 * DD / 4 / 256;               // 2048 feature blocks
    if (blockIdx.x < NB_X) {
        int i = blockIdx.x * 256 + threadIdx.x;
        const int per = NT * DD / 4;
        bool sideB = i >= per;
        const float4* src = (const float4*)(sideB ? b : a);
        float4 v = src[sideB ? i - per : i];
        float dv = dinv[i / (DD / 4)];
        ushort4 o;
        o.x = f2b(v.x * dv); o.y = f2b(v.y * dv); o.z = f2b(v.z * dv); o.w = f2b(v.w * dv);
        ((ushort4*)out)[i] = o;
    } else {
        int i = (blockIdx.x - NB_X) * 256 + threadIdx.x;   // 0..16383
        if (i < DD * F1C)  { int k = i / F1C, n = i % F1C; Wt1[n * DD + k]  = f2b(W1[i]); }
        if (i < F1C * F2C) { int k = i / F2C, n = i % F2C; Wt2[n * F1C + k] = f2b(W2[i]); }
        if (i < F2C * F3C) { int k = i / F3C, n = i % F3C; Wt3f8[n * F2C + k] = f2f8(W3[i]); }
    }
}

// ---------------- GCN aggregation, bf16 rows (layer 1, F=32) ----------------
template<int F, bool BIAS, bool RELU>
__global__ __launch_bounds__(256) void agg_bf_k(const ushort* __restrict__ in, const int* __restrict__ rp,
                                                const int* __restrict__ indeg, const int* __restrict__ ep,
                                                const float* __restrict__ dinv,
                                                const float* __restrict__ bias, ushort* __restrict__ out) {
    constexpr int LPV = F / 8;
    constexpr int VPB = 256 / LPV;
    int g = threadIdx.x / LPV;
    int l = threadIdx.x % LPV;
    int v = blockIdx.x * VPB + g;
    float dv = dinv[v];
    short8 rs = *(const short8*)(in + (size_t)v * F + l * 8);
    float acc[8];
#pragma unroll
    for (int j = 0; j < 8; j++) acc[j] = b2f((ushort)rs[j]);
    int start = rp[v];
    int cnt   = indeg[v];
    int i = 0;
    for (; i + 4 <= cnt; i += 4) {
        int s0 = ep[start + i];
        int s1 = ep[start + i + 1];
        int s2 = ep[start + i + 2];
        int s3 = ep[start + i + 3];
        short8 r0 = *(const short8*)(in + (size_t)s0 * F + l * 8);
        short8 r1 = *(const short8*)(in + (size_t)s1 * F + l * 8);
        short8 r2 = *(const short8*)(in + (size_t)s2 * F + l * 8);
        short8 r3 = *(const short8*)(in + (size_t)s3 * F + l * 8);
#pragma unroll
        for (int j = 0; j < 8; j++) {
            acc[j] += b2f((ushort)r0[j]);
            acc[j] += b2f((ushort)r1[j]);
            acc[j] += b2f((ushort)r2[j]);
            acc[j] += b2f((ushort)r3[j]);
        }
    }
    for (; i < cnt; i++) {
        int s0 = ep[start + i];
        short8 r0 = *(const short8*)(in + (size_t)s0 * F + l * 8);
#pragma unroll
        for (int j = 0; j < 8; j++) acc[j] += b2f((ushort)r0[j]);
    }
    short8 o;
#pragma unroll
    for (int j = 0; j < 8; j++) {
        float x = dv * acc[j];
        if (BIAS) x += bias[l * 8 + j];
        if (RELU) x = fmaxf(x, 0.0f);
        o[j] = (short)f2b(x);
    }
    *(short8*)(out + (size_t)v * F + l * 8) = o;
}

// ---------------- GCN aggregation, fp8 rows (F=64), edge loop unrolled x8 ----------------
template<bool OUT_BF16, bool BIAS, bool RELU>
__global__ __launch_bounds__(256) void agg_f8_k(const uchar* __restrict__ in, const int* __restrict__ rp,
                                                const int* __restrict__ indeg, const int* __restrict__ ep,
                                                const float* __restrict__ dinv,
                                                const float* __restrict__ bias, void* __restrict__ outp) {
    int g = threadIdx.x >> 3;          // 32 vertices per block
    int l = threadIdx.x & 7;           // 8 lanes x 8 fp8 = 64 B row
    int v = blockIdx.x * 32 + g;
    float dv = dinv[v];
    float acc[8] = {0, 0, 0, 0, 0, 0, 0, 0};
    f8x8_acc(*(const uint2*)(in + (size_t)v * 64 + l * 8), acc);   // self term
    int start = rp[v];
    int cnt   = indeg[v];
    int i = 0;
    for (; i + 8 <= cnt; i += 8) {     // 8 gathers in flight per lane
        int sx[8];
#pragma unroll
        for (int j = 0; j < 8; j++) sx[j] = ep[start + i + j];
        uint2 gx[8];
#pragma unroll
        for (int j = 0; j < 8; j++) gx[j] = *(const uint2*)(in + (size_t)sx[j] * 64 + l * 8);
#pragma unroll
        for (int j = 0; j < 8; j++) f8x8_acc(gx[j], acc);
    }
    for (; i + 4 <= cnt; i += 4) {
        int s0 = ep[start + i];
        int s1 = ep[start + i + 1];
        int s2 = ep[start + i + 2];
        int s3 = ep[start + i + 3];
        uint2 g0 = *(const uint2*)(in + (size_t)s0 * 64 + l * 8);
        uint2 g1 = *(const uint2*)(in + (size_t)s1 * 64 + l * 8);
        uint2 g2 = *(const uint2*)(in + (size_t)s2 * 64 + l * 8);
        uint2 g3 = *(const uint2*)(in + (size_t)s3 * 64 + l * 8);
        f8x8_acc(g0, acc); f8x8_acc(g1, acc); f8x8_acc(g2, acc); f8x8_acc(g3, acc);
    }
    for (; i < cnt; i++) {
        int s0 = ep[start + i];
        f8x8_acc(*(const uint2*)(in + (size_t)s0 * 64 + l * 8), acc);
    }
#pragma unroll
    for (int j = 0; j < 8; j++) {
        float x = dv * acc[j];
        if (BIAS) x += bias[l * 8 + j];
        if (RELU) x = fmaxf(x, 0.0f);
        acc[j] = x;
    }
    if (OUT_BF16) {
        short8 o;
#pragma unroll
        for (int j = 0; j < 8; j++) o[j] = (short)f2b(acc[j]);
        *(short8*)((ushort*)outp + (size_t)v * 64 + l * 8) = o;
    } else {
        *(uint2*)((uchar*)outp + (size_t)v * 64 + l * 8) = f8x8_pack(acc);
    }
}

// ---------------- fused GEMM1+GEMM2: h1=relu(xa@W1+b1) [LDS] ; out8=(h1@W2)*dinv ----------
__global__ __launch_bounds__(256) void gemm12_k(const ushort* __restrict__ xa,
                                                const ushort* __restrict__ Wt1,
                                                const float* __restrict__ b1,
                                                const ushort* __restrict__ Wt2,
                                                const float* __restrict__ dinv,
                                                uchar* __restrict__ h8a) {
    __shared__ ushort s_h1[128][136];
    int w = threadIdx.x >> 6, lane = threadIdx.x & 63;
    int r16 = lane & 15, quad = lane >> 4, koff = quad * 8;
    size_t rows0 = (size_t)blockIdx.x * 128;

    short8 af1[2];
#pragma unroll
    for (int mt = 0; mt < 2; mt++)
        af1[mt] = *(const short8*)(xa + (rows0 + (w * 2 + mt) * 16 + r16) * 32 + koff);
#pragma unroll
    for (int nt = 0; nt < 8; nt++) {
        short8 bfr = *(const short8*)(Wt1 + (size_t)(nt * 16 + r16) * 32 + koff);
        f32x4 acc[2] = {{0.f,0.f,0.f,0.f},{0.f,0.f,0.f,0.f}};
        acc[0] = __builtin_amdgcn_mfma_f32_16x16x32_bf16(af1[0], bfr, acc[0], 0, 0, 0);
        acc[1] = __builtin_amdgcn_mfma_f32_16x16x32_bf16(af1[1], bfr, acc[1], 0, 0, 0);
        int col = nt * 16 + r16;
        float bc = b1[col];
#pragma unroll
        for (int mt = 0; mt < 2; mt++)
#pragma unroll
            for (int r = 0; r < 4; r++) {
                int rl = (w * 2 + mt) * 16 + quad * 4 + r;
                s_h1[rl][col] = f2b(fmaxf(acc[mt][r] + bc, 0.0f));
            }
    }
    __syncthreads();

    short8 af2[4][2];
#pragma unroll
    for (int kc = 0; kc < 4; kc++)
#pragma unroll
        for (int mt = 0; mt < 2; mt++)
            af2[kc][mt] = *(const short8*)&s_h1[(w * 2 + mt) * 16 + r16][kc * 32 + koff];
    float dvr[2][4];
#pragma unroll
    for (int mt = 0; mt < 2; mt++)
#pragma unroll
        for (int r = 0; r < 4; r++)
            dvr[mt][r] = dinv[rows0 + (w * 2 + mt) * 16 + quad * 4 + r];
#pragma unroll
    for (int nt = 0; nt < 4; nt++) {
        f32x4 acc[2] = {{0.f,0.f,0.f,0.f},{0.f,0.f,0.f,0.f}};
#pragma unroll
        for (int kc = 0; kc < 4; kc++) {
            short8 bfr = *(const short8*)(Wt2 + (size_t)(nt * 16 + r16) * 128 + kc * 32 + koff);
            acc[0] = __builtin_amdgcn_mfma_f32_16x16x32_bf16(af2[kc][0], bfr, acc[0], 0, 0, 0);
            acc[1] = __builtin_amdgcn_mfma_f32_16x16x32_bf16(af2[kc][1], bfr, acc[1], 0, 0, 0);
        }
#pragma unroll
        for (int mt = 0; mt < 2; mt++)
#pragma unroll
            for (int r = 0; r < 4; r++) {
                size_t row = rows0 + (w * 2 + mt) * 16 + quad * 4 + r;
                int col = nt * 16 + r16;
                h8a[row * 64 + col] = f2f8(acc[mt][r] * dvr[mt][r]);
            }
    }
}

// ---------------- fp8 GEMM via MFMA (K=64, N=64) ----------------
__global__ __launch_bounds__(256) void gemm_f8_k(const uchar* __restrict__ A8,
                                                 const uchar* __restrict__ Wt8,
                                                 const float* __restrict__ dinv,
                                                 uchar* __restrict__ out8) {
    int w = threadIdx.x >> 6, lane = threadIdx.x & 63;
    int r16 = lane & 15, koff = (lane >> 4) * 8;
    size_t rows0 = (size_t)blockIdx.x * 128;

    long af[2][2];
#pragma unroll
    for (int kc = 0; kc < 2; kc++)
#pragma unroll
        for (int mt = 0; mt < 2; mt++)
            af[kc][mt] = *(const long*)(A8 + (rows0 + (w * 2 + mt) * 16 + r16) * 64 + kc * 32 + koff);

    float dvr[2][4];
#pragma unroll
    for (int mt = 0; mt < 2; mt++)
#pragma unroll
        for (int r = 0; r < 4; r++)
            dvr[mt][r] = dinv[rows0 + (w * 2 + mt) * 16 + (lane >> 4) * 4 + r];

#pragma unroll
    for (int nt = 0; nt < 4; nt++) {
        f32x4 acc[2] = {{0.f,0.f,0.f,0.f},{0.f,0.f,0.f,0.f}};
#pragma unroll
        for (int kc = 0; kc < 2; kc++) {
            long b = *(const long*)(Wt8 + (size_t)(nt * 16 + r16) * 64 + kc * 32 + koff);
            acc[0] = __builtin_amdgcn_mfma_f32_16x16x32_fp8_fp8(af[kc][0], b, acc[0], 0, 0, 0);
            acc[1] = __builtin_amdgcn_mfma_f32_16x16x32_fp8_fp8(af[kc][1], b, acc[1], 0, 0, 0);
        }
#pragma unroll
        for (int mt = 0; mt < 2; mt++) {
#pragma unroll
            for (int r = 0; r < 4; r++) {
                size_t row = rows0 + (w * 2 + mt) * 16 + (lane >> 4) * 4 + r;
                int col = nt * 16 + (lane & 15);
                out8[row * 64 + col] = f2f8(acc[mt][r] * dvr[mt][r]);
            }
        }
    }
}

// ---------------- fused pool + hist: blocks [0,512) pool, [512,768) hist ----------------
// pool: 16B/lane vector loads; hist: cb staged once in LDS ([256][72] ushort, 2-way-free banks)
__global__ __launch_bounds__(256) void pool_hist_k(const ushort* __restrict__ fin,
                                                   const int* __restrict__ qsz, const int* __restrict__ csz,
                                                   const float* __restrict__ attn_w,
                                                   float* __restrict__ e_out, float* __restrict__ histp) {
    __shared__ float smemf[17472];     // 69.9 KB union scratch
    int t = threadIdx.x;
    if (blockIdx.x < 512) {
        // ---- pool path ----
        int b = blockIdx.x & 255;
        bool is_c = blockIdx.x >= BB;
        const ushort* emb = fin + (size_t)blockIdx.x * NN * F3C;
        float size = (float)((is_c ? csz : qsz)[b]);
        float* eo = e_out + (is_c ? BB * F3C : 0) + b * F3C;
        float (*s_emb)[F3C + 1] = (float(*)[F3C + 1])smemf;      // 256*65
        float* s_red = smemf + 256 * 65;                          // 4*64
        float* s_sq  = s_red + 256;                               // 64
        float* s_ctx = s_sq + 64;                                 // 64
        float* s_sig = s_ctx + 64;                                // 256
        int f = t & 63;
        int w = t >> 6;
        // phase 1: vectorized load (16 B/lane, fully coalesced)
#pragma unroll
        for (int it = 0; it < 8; it++) {
            int idx = it * 2048 + t * 8;
            int row = idx >> 6, f0 = idx & 63;
            short8 v = *(const short8*)(emb + idx);
#pragma unroll
            for (int j = 0; j < 8; j++) s_emb[row][f0 + j] = b2f((ushort)v[j]);
        }
        __syncthreads();
        // phase 2: column sums (wave w covers rows [64w, 64w+64))
        float psum = 0.0f;
#pragma unroll 8
        for (int i2 = 0; i2 < 64; i2++) psum += s_emb[w * 64 + i2][f];
        s_red[w * 64 + f] = psum;
        __syncthreads();
        if (w == 0) {
            s_sq[f] = s_red[f] + s_red[64 + f] + s_red[128 + f] + s_red[192 + f];
            float acc = 0.0f;
            for (int k = 0; k < 64; k++) acc += s_sq[k] * attn_w[k * 64 + f];
            s_ctx[f] = tanhf(acc / size);
        }
        __syncthreads();
        {
            float acc = 0.0f;
#pragma unroll 8
            for (int k = 0; k < 64; k++) acc += s_emb[t][k] * s_ctx[k];
            s_sig[t] = 1.0f / (1.0f + expf(-acc));
        }
        __syncthreads();
        float eacc = 0.0f;
#pragma unroll 8
        for (int i = 0; i < 64; i++) {
            int n = w * 64 + i;
            eacc += s_sig[n] * s_emb[n][f];
        }
        s_red[w * 64 + f] = eacc;
        __syncthreads();
        if (w == 0) eo[f] = s_red[f] + s_red[64 + f] + s_red[128 + f] + s_red[192 + f];
    } else {
        // ---- hist path (cb LDS-staged) ----
        int b = blockIdx.x - 512;
        const ushort* qb = fin + (size_t)b * NN * 64;
        const ushort* cb = fin + (size_t)(NT + b * NN) * 64;   // cfin
        int lane = t & 63;
        int w = t >> 6;
        int r16 = lane & 15, koff = (lane >> 4) * 8;
        ushort (*cb_s)[72] = (ushort(*)[72])smemf;              // 256*72 ushorts = 36.9 KB
        int* h = (int*)(smemf + 9216);                          // 16*256 ints (at 36.9KB offset)
        int* hp = h + 16 * 256;                                 // 16*16
        float* smn = (float*)(hp + 256);                        // 4
        float* smx = smn + 4;                                   // 4
        float* s_sc = smx + 4;                                  // 2: {mn, scale}

        // stage cb: 16 B/lane coalesced global -> LDS (aligned: 144 B row pitch)
#pragma unroll
        for (int it = 0; it < 8; it++) {
            int idx = it * 2048 + t * 8;
            int row = idx >> 6, f0 = idx & 63;
            *(short8*)&cb_s[row][f0] = *(const short8*)(cb + idx);
        }
        // q fragments in registers
        short8 a[4][2];
#pragma unroll
        for (int i = 0; i < 4; i++) {
            int row = (w * 4 + i) * 16 + r16;
#pragma unroll
            for (int kk = 0; kk < 2; kk++)
                a[i][kk] = *(const short8*)(qb + row * 64 + kk * 32 + koff);
        }
        __syncthreads();
        // pass A: min/max (cb from LDS)
        float mn = 1e30f, mx = -1e30f;
        for (int mt = 0; mt < 16; mt++) {
            int crow = mt * 16 + r16;
            short8 b0 = *(const short8*)&cb_s[crow][koff];
            short8 b1 = *(const short8*)&cb_s[crow][32 + koff];
#pragma unroll
            for (int i = 0; i < 4; i++) {
                f32x4 acc = {0.0f, 0.0f, 0.0f, 0.0f};
                acc = __builtin_amdgcn_mfma_f32_16x16x32_bf16(a[i][0], b0, acc, 0, 0, 0);
                acc = __builtin_amdgcn_mfma_f32_16x16x32_bf16(a[i][1], b1, acc, 0, 0, 0);
                mn = fminf(mn, fminf(fminf(acc[0], acc[1]), fminf(acc[2], acc[3])));
                mx = fmaxf(mx, fmaxf(fmaxf(acc[0], acc[1]), fmaxf(acc[2], acc[3])));
            }
        }
        for (int off = 32; off; off >>= 1) {
            mn = fminf(mn, __shfl_xor(mn, off, 64));
            mx = fmaxf(mx, __shfl_xor(mx, off, 64));
        }
        if (lane == 0) { smn[w] = mn; smx[w] = mx; }
        __syncthreads();
        if (t == 0) {
            float m0 = fminf(fminf(smn[0], smn[1]), fminf(smn[2], smn[3]));
            float m1 = fmaxf(fmaxf(smx[0], smx[1]), fmaxf(smx[2], smx[3]));
            s_sc[0] = m0;
            s_sc[1] = 16.0f / fmaxf(m1 - m0, 1e-12f);
        }
#pragma unroll
        for (int i = 0; i < 16; i++) h[i * 256 + t] = 0;
        __syncthreads();
        float bmn = s_sc[0], bscale = s_sc[1];
        // pass B: recompute and bin (cb from LDS, per-thread slots)
        for (int mt = 0; mt < 16; mt++) {
            int crow = mt * 16 + r16;
            short8 b0 = *(const short8*)&cb_s[crow][koff];
            short8 b1 = *(const short8*)&cb_s[crow][32 + koff];
#pragma unroll
            for (int i = 0; i < 4; i++) {
                f32x4 acc = {0.0f, 0.0f, 0.0f, 0.0f};
                acc = __builtin_amdgcn_mfma_f32_16x16x32_bf16(a[i][0], b0, acc, 0, 0, 0);
                acc = __builtin_amdgcn_mfma_f32_16x16x32_bf16(a[i][1], b1, acc, 0, 0, 0);
#pragma unroll
                for (int r = 0; r < 4; r++) {
                    int bin = (int)floorf((acc[r] - bmn) * bscale);
                    bin = min(max(bin, 0), 15);
                    h[bin * 256 + t] += 1;
                }
            }
        }
        __syncthreads();
        int bb = t >> 4, part = t & 15;
        int sum = 0;
#pragma unroll
        for (int j = 0; j < 16; j++) sum += h[bb * 256 + part * 16 + j];
        hp[bb * 16 + part] = sum;
        __syncthreads();
        if (t < 16) {
            int s = 0;
#pragma unroll
            for (int j = 0; j < 16; j++) s += hp[t * 16 + j];
            histp[b * 16 + t] = (float)s;
        }
    }
}

// ---------------- NTN + head fused ----------------
__global__ __launch_bounds__(256) void ntn_final_k(const float* __restrict__ e, const float* __restrict__ A,
                                                   const float* __restrict__ bw, const float* __restrict__ bias,
                                                   const float* __restrict__ histp,
                                                   const float* __restrict__ fc1w, const float* __restrict__ fc1b,
                                                   const float* __restrict__ fc2w, const float* __restrict__ fc2b,
                                                   const int* __restrict__ qsz, const int* __restrict__ csz,
                                                   float* __restrict__ out) {
    int b = blockIdx.x;
    int t = threadIdx.x;
    __shared__ float s_e1[64], s_e2[64];
    __shared__ float s_ntn[16];
    __shared__ float s_s[32];
    __shared__ float s_a[16];
    if (t < 64) s_e1[t] = e[b * 64 + t];
    else if (t < 128) s_e2[t - 64] = e[BB * 64 + b * 64 + (t - 64)];
    if (t < 16) s_ntn[t] = 0.0f;
    __syncthreads();
#pragma unroll
    for (int r = 0; r < 4; r++) {
        int idx = t + r * 256;
        int tt = idx >> 6, i = idx & 63;
        const float* Ar = A + (size_t)idx * 64;
        float acc = 0.0f;
        for (int j = 0; j < 64; j++) acc += Ar[j] * s_e2[j];
        atomicAdd(&s_ntn[tt], s_e1[i] * acc);
    }
    __syncthreads();
    if (t < 16) {
        float acc = s_ntn[t] + bias[t];
        for (int k = 0; k < 64; k++) acc += s_e1[k] * bw[k * 16 + t];
        for (int k = 0; k < 64; k++) acc += s_e2[k] * bw[(64 + k) * 16 + t];
        s_s[t] = fmaxf(acc, 0.0f);
        s_s[16 + t] = histp[b * 16 + t] * (1.0f / 65536.0f);
    }
    __syncthreads();
    if (t < 16) {
        float a = fc1b[t];
        for (int k = 0; k < 32; k++) a += s_s[k] * fc1w[k * 16 + t];
        s_a[t] = fmaxf(a, 0.0f);
    }
    __syncthreads();
    if (t == 0) {
        float z = fc2b[0];
        for (int j = 0; j < 16; j++) z += s_a[j] * fc2w[j];
        float nz = -z;
        float sp = (nz > 20.0f) ? nz : log1pf(expf(nz));   // stable -log(sigmoid(z))
        out[b] = 0.5f * (float)(qsz[b] + csz[b]) * sp;
    }
}

// ---------------- launch ----------------
extern "C" void kernel_launch(void* const* d_in, const int* in_sizes, int n_in,
                              void* d_out, int out_size, void* d_ws, size_t ws_size,
                              hipStream_t stream) {
    const float* x_q    = (const float*)d_in[0];
    const int*   edge_q = (const int*)d_in[1];
    const float* x_c    = (const float*)d_in[2];
    const int*   edge_c = (const int*)d_in[3];
    const int*   qsz    = (const int*)d_in[4];
    const int*   csz    = (const int*)d_in[5];
    const float* W1 = (const float*)d_in[6];
    const float* b1 = (const float*)d_in[7];
    const float* W2 = (const float*)d_in[8];
    const float* b2 = (const float*)d_in[9];
    const float* W3 = (const float*)d_in[10];
    const float* b3 = (const float*)d_in[11];
    const float* attn_w  = (const float*)d_in[12];
    const float* ntn_a   = (const float*)d_in[13];
    const float* ntn_b   = (const float*)d_in[14];
    const float* ntn_bias= (const float*)d_in[15];
    const float* fc1w = (const float*)d_in[16];
    const float* fc1b = (const float*)d_in[17];
    const float* fc2w = (const float*)d_in[18];
    const float* fc2b = (const float*)d_in[19];
    float* out = (float*)d_out;

    char* w = (char*)d_ws;
    auto alloc = [&](size_t bytes) -> void* {
        void* p = (void*)w;
        w += (bytes + 255) & ~(size_t)255;
        return p;
    };
    int*    rp     = (int*)alloc((size_t)NT2 * 4);
    int*    indeg  = (int*)alloc((size_t)NT2 * 4);
    float*  dinv   = (float*)alloc((size_t)NT2 * 4);
    int*    gcount = (int*)alloc(NBUCK * 4);
    uint*   staged = (uint*)alloc((size_t)NBUCK * BCAP * 4);   // 10.5 MB packed
    int*    ep     = (int*)alloc((size_t)2 * NE * 4);           // 8.4 MB (src only)
    ushort* xb     = (ushort*)alloc((size_t)NT2 * 32 * 2);
    ushort* xa     = (ushort*)alloc((size_t)NT2 * 32 * 2);
    uchar*  h8a    = (uchar*)alloc((size_t)NT2 * 64);           // fp8 64-d scratch
    uchar*  h8b    = (uchar*)alloc((size_t)NT2 * 64);           // fp8 64-d scratch
    ushort* fin    = (ushort*)alloc((size_t)NT2 * 64 * 2);      // qfin | cfin (bf16)
    ushort* Wt1    = (ushort*)alloc((size_t)DD * F1C * 2);
    ushort* Wt2    = (ushort*)alloc((size_t)F1C * F2C * 2);
    uchar*  Wt3f8  = (uchar*)alloc((size_t)F2C * F3C);
    float*  e12    = (float*)alloc(2 * BB * 64 * 4);
    float*  histp  = (float*)alloc(256 * 16 * 4);

    // CSR build (unified graph)
    zero_k<<<1, 256, 0, stream>>>(gcount);
    csr_p1_k<<<512, 256, 0, stream>>>(edge_q, edge_c, staged, gcount);
    csr_p2_k<<<NBUCK, 256, 0, stream>>>(staged, gcount, rp, indeg, dinv, ep);

    // features -> pre-scaled bf16 + weight conversions (one launch)
    cvt2w_k<<<NT2 * 32 / 4 / 256 + 64, 256, 0, stream>>>(x_q, x_c, dinv, xb,
                                                         W1, W2, W3, Wt1, Wt2, Wt3f8);

    // GNN: agg1 -> fused gemm1+2 -> agg2 -> gemm3(fp8) -> agg3
    agg_bf_k<32, false, false><<<NT2 / 64, 256, 0, stream>>>(xb, rp, indeg, ep, dinv, nullptr, xa);
    gemm12_k<<<NT2 / 128, 256, 0, stream>>>(xa, Wt1, b1, Wt2, dinv, h8a);
    agg_f8_k<false, true, true><<<NT2 / 32, 256, 0, stream>>>(h8a, rp, indeg, ep, dinv, b2, h8b);
    gemm_f8_k<<<NT2 / 128, 256, 0, stream>>>(h8b, Wt3f8, dinv, h8a);
    agg_f8_k<true, true, false><<<NT2 / 32, 256, 0, stream>>>(h8a, rp, indeg, ep, dinv, b3, fin);

    // pool + hist fused (independent consumers of fin), then NTN+head
    pool_hist_k<<<768, 256, 0, stream>>>(fin, qsz, csz, attn_w, e12, histp);
    ntn_final_k<<<BB, 256, 0, stream>>>(e12, ntn_a, ntn_b, ntn_bias, histp,
                                        fc1w, fc1b, fc2w, fc2b, qsz, csz, out);
}